// Round 5
// baseline (61.365 us; speedup 1.0000x reference)
//
#include <hip/hip_runtime.h>
#include <math.h>

#define NBATCH 16
#define NATOM  512
#define NEIGH  64
#define PPM    (NATOM * NEIGH)      // 32768 = 2^15
#define NPAIR  (NBATCH * PPM)       // 524288
#define TOTATOM (NBATCH * NATOM)    // 8192
#define NTYPE  4
#define NWAVE  8
#define MAXN   128                  // slot capacity per atom (avg 64; Poisson tail safe at 128)
#define PI_OVER_CUTOFF 0.6283185307179586f

typedef float nfloat4 __attribute__((ext_vector_type(4)));

// ---- workspace layout (bytes) ----
// cursors : int[8192]                      @ 0        (32 KB)
// records : float4[TOTATOM * MAXN] (16 MB) @ 32768
#define WS_OFF_RECORDS 32768

// Zero per-atom cursors (custom kernel: hipMemsetAsync node cost ~40 us in round 0).
__global__ __launch_bounds__(256) void zero_kernel(int4* __restrict__ cursors4)
{
    int gid = blockIdx.x * 256 + threadIdx.x;   // grid = 8 blocks -> 2048 int4 = 8192 ints
    cursors4[gid] = make_int4(0, 0, 0, 0);
}

// Batch<->XCD affinity: 128 consecutive work-chunks per batch; put batch b's
// blocks on XCD b&7 (round-robin blockIdx->XCD heuristic). All stores to
// batch b's 1MB record slab and 2KB of cursors then stay in ONE XCD's L2:
// full-line write merging, no cross-XCD atomic ping-pong, and density
// (same swizzle) reads the records back from the local L2.
__device__ __forceinline__ int swizzle_chunk(int bx, int* batch)
{
    int xcd = bx & 7;
    int j   = bx >> 3;            // 0..255
    *batch  = xcd + ((j >> 7) << 3);   // two batches per XCD
    return j & 127;               // chunk within batch, 0..127
}

// One pass over all pairs: claim a slot via atomic cursor, store
// (cart[i1]-shift, species). cart[i0] is applied in density (uniform there).
// Plain stores on purpose: nontemporal stores regressed by ~4 us (round 3/4
// A/B) — nt bypasses L2, so random 16B stores become partial-line HBM
// write-throughs instead of L2-merged dirty lines.
__global__ __launch_bounds__(256) void scatter_kernel(
    const int* __restrict__ atom_index, const float* __restrict__ shifts,
    const float* __restrict__ cart, const int* __restrict__ species,
    int* __restrict__ cursors, nfloat4* __restrict__ records)
{
    int b;
    int chunk = swizzle_chunk(blockIdx.x, &b);       // grid = 2048 blocks
    int gid = b * PPM + chunk * 256 + threadIdx.x;   // coalesced within block
    float s0 = shifts[gid * 3 + 0];
    float s1 = shifts[gid * 3 + 1];
    float s2 = shifts[gid * 3 + 2];
    if (!(s0 > -1e10f && s1 > -1e10f && s2 > -1e10f)) return;
    int i0 = atom_index[gid] + b * NATOM;
    int i1 = atom_index[NPAIR + gid] + b * NATOM;
    int pos = atomicAdd(&cursors[i0], 1);
    if (pos >= MAXN) return;                         // safety clamp (never hit here)
    nfloat4 r;
    r.x = cart[i1 * 3 + 0] - s0;
    r.y = cart[i1 * 3 + 1] - s1;
    r.z = cart[i1 * 3 + 2] - s2;
    r.w = __int_as_float(species[i1]);
    records[i0 * MAXN + pos] = r;
}

__global__ __launch_bounds__(256) void density_kernel(
    const nfloat4* __restrict__ records, const int* __restrict__ cursors,
    const float* __restrict__ cart,
    const float* __restrict__ rs, const float* __restrict__ inta,
    const float* __restrict__ params, float* __restrict__ out)
{
    __shared__ float s_rs[NTYPE * NWAVE];
    __shared__ float s_ia[NTYPE * NWAVE];
    __shared__ float s_pm[NTYPE * NWAVE];
    if (threadIdx.x < NTYPE * NWAVE) {
        s_rs[threadIdx.x] = rs[threadIdx.x];
        s_ia[threadIdx.x] = inta[threadIdx.x];
        s_pm[threadIdx.x] = params[threadIdx.x];
    }
    __syncthreads();

    int b;
    int chunk = swizzle_chunk(blockIdx.x, &b);       // same mapping as scatter
    int atom = b * NATOM + chunk * 4 + (threadIdx.x >> 6);
    int lane = threadIdx.x & 63;
    int w    = lane & 7;        // basis index
    int rsub = lane >> 3;       // record subset 0..7

    int n = cursors[atom];
    if (n > MAXN) n = MAXN;
    const nfloat4* rec = records + (size_t)atom * MAXN;

    float cx = cart[atom * 3 + 0];
    float cy = cart[atom * 3 + 1];
    float cz = cart[atom * 3 + 2];

    float a0 = 0.f, a1 = 0.f, a2 = 0.f, a3 = 0.f, a4 = 0.f;
    float a5 = 0.f, a6 = 0.f, a7 = 0.f, a8 = 0.f, a9 = 0.f;

    for (int k = rsub; k < n; k += 8) {
        nfloat4 r = rec[k];                      // lanes 0-7 broadcast; wave = 128B line
        float dx = cx - r.x, dy = cy - r.y, dz = cz - r.z;
        int sp = __float_as_int(r.w);
        float d2 = dx * dx + dy * dy + dz * dz;
        float d  = sqrtf(d2);
        float c  = 0.5f * cosf(d * PI_OVER_CUTOFF) + 0.5f;
        float fc = c * c;
        int ti = sp * NWAVE + w;
        float t = d - s_rs[ti];
        float g = fc * s_pm[ti] * expf(-s_ia[ti] * t * t);
        a0 += g;
        a1 += g * dx; a2 += g * dy; a3 += g * dz;
        a4 += g * dx * dx; a5 += g * dx * dy; a6 += g * dx * dz;
        a7 += g * dy * dy; a8 += g * dy * dz; a9 += g * dz * dz;
    }

#define RED(v) { v += __shfl_xor(v, 8); v += __shfl_xor(v, 16); v += __shfl_xor(v, 32); }
    RED(a0) RED(a1) RED(a2) RED(a3) RED(a4)
    RED(a5) RED(a6) RED(a7) RED(a8) RED(a9)
#undef RED

    if (rsub == 0) {
        float* o = out + (size_t)atom * 24;
        o[w]      = a0 * a0;
        o[8 + w]  = a1 * a1 + a2 * a2 + a3 * a3;
        o[16 + w] = a4 * a4 + a7 * a7 + a9 * a9
                  + 2.0f * (a5 * a5 + a6 * a6 + a8 * a8);
    }
}

extern "C" void kernel_launch(void* const* d_in, const int* in_sizes, int n_in,
                              void* d_out, int out_size, void* d_ws, size_t ws_size,
                              hipStream_t stream)
{
    const float* cart      = (const float*)d_in[0];
    // d_in[1] = numatoms (unused by reference math)
    const int*   species   = (const int*)d_in[2];
    const int*   atom_index= (const int*)d_in[3];
    const float* shifts    = (const float*)d_in[4];
    const float* rs        = (const float*)d_in[5];
    const float* inta      = (const float*)d_in[6];
    const float* params    = (const float*)d_in[7];
    float* out = (float*)d_out;

    char* ws = (char*)d_ws;
    int*     cursors = (int*)ws;
    nfloat4* records = (nfloat4*)(ws + WS_OFF_RECORDS);

    zero_kernel<<<TOTATOM / 1024, 256, 0, stream>>>((int4*)cursors);
    scatter_kernel<<<NPAIR / 256, 256, 0, stream>>>(
        atom_index, shifts, cart, species, cursors, records);
    density_kernel<<<TOTATOM / 4, 256, 0, stream>>>(
        records, cursors, cart, rs, inta, params, out);
}

// Round 6
// 51.423 us; speedup vs baseline: 1.1934x; 1.1934x over previous
//
#include <hip/hip_runtime.h>
#include <math.h>

#define NBATCH 16
#define NATOM  512
#define NEIGH  64
#define PPM    (NATOM * NEIGH)      // 32768 = 2^15
#define NPAIR  (NBATCH * PPM)       // 524288
#define TOTATOM (NBATCH * NATOM)    // 8192
#define NTYPE  4
#define NWAVE  8
#define MAXN   128                  // slot capacity per atom (avg 64; Poisson tail safe at 128)

typedef float nfloat4 __attribute__((ext_vector_type(4)));

// ---- workspace layout (bytes) ----
// cursors : int[8192]                      @ 0        (32 KB)
// records : float4[TOTATOM * MAXN] (16 MB) @ 32768
#define WS_OFF_RECORDS 32768

// Zero per-atom cursors (custom kernel: hipMemsetAsync node cost ~40 us in round 0).
__global__ __launch_bounds__(256) void zero_kernel(int4* __restrict__ cursors4)
{
    int gid = blockIdx.x * 256 + threadIdx.x;   // grid = 8 blocks -> 2048 int4 = 8192 ints
    cursors4[gid] = make_int4(0, 0, 0, 0);
}

// One pass over all pairs: claim a slot via atomic cursor, store
// (cart[i1]-shift, species). cart[i0] is applied in density (uniform there).
// Plain stores on purpose: nontemporal stores regressed ~4 us (R3/R4 A/B) —
// nt bypasses L2 so random 16B stores become partial-line HBM write-throughs.
// NO XCD swizzle on purpose: batch->XCD affinity regressed ~4.5 us (R5).
__global__ __launch_bounds__(256) void scatter_kernel(
    const int* __restrict__ atom_index, const float* __restrict__ shifts,
    const float* __restrict__ cart, const int* __restrict__ species,
    int* __restrict__ cursors, nfloat4* __restrict__ records)
{
    int gid = blockIdx.x * 256 + threadIdx.x;   // grid = NPAIR/256 = 2048 blocks
    float s0 = shifts[gid * 3 + 0];
    float s1 = shifts[gid * 3 + 1];
    float s2 = shifts[gid * 3 + 2];
    if (!(s0 > -1e10f && s1 > -1e10f && s2 > -1e10f)) return;
    int b  = gid >> 15;                         // PPM = 2^15
    int i0 = atom_index[gid] + b * NATOM;
    int i1 = atom_index[NPAIR + gid] + b * NATOM;
    int pos = atomicAdd(&cursors[i0], 1);
    if (pos >= MAXN) return;                    // safety clamp (never hit here)
    nfloat4 r;
    r.x = cart[i1 * 3 + 0] - s0;
    r.y = cart[i1 * 3 + 1] - s1;
    r.z = cart[i1 * 3 + 2] - s2;
    r.w = __int_as_float(species[i1]);
    records[i0 * MAXN + pos] = r;
}

__global__ __launch_bounds__(256) void density_kernel(
    const nfloat4* __restrict__ records, const int* __restrict__ cursors,
    const float* __restrict__ cart,
    const float* __restrict__ rs, const float* __restrict__ inta,
    const float* __restrict__ params, float* __restrict__ out)
{
    __shared__ float s_rs[NTYPE * NWAVE];
    __shared__ float s_ia[NTYPE * NWAVE];
    __shared__ float s_pm[NTYPE * NWAVE];
    if (threadIdx.x < NTYPE * NWAVE) {
        s_rs[threadIdx.x] = rs[threadIdx.x];
        s_ia[threadIdx.x] = inta[threadIdx.x];
        s_pm[threadIdx.x] = params[threadIdx.x];
    }
    __syncthreads();

    int atom = blockIdx.x * 4 + (threadIdx.x >> 6);  // grid = TOTATOM/4 = 2048
    int lane = threadIdx.x & 63;
    int w    = lane & 7;        // basis index
    int rsub = lane >> 3;       // record subset 0..7

    int n = cursors[atom];
    if (n > MAXN) n = MAXN;
    const nfloat4* rec = records + (size_t)atom * MAXN;

    float cx = cart[atom * 3 + 0];
    float cy = cart[atom * 3 + 1];
    float cz = cart[atom * 3 + 2];

    float a0 = 0.f, a1 = 0.f, a2 = 0.f, a3 = 0.f, a4 = 0.f;
    float a5 = 0.f, a6 = 0.f, a7 = 0.f, a8 = 0.f, a9 = 0.f;

    for (int k = rsub; k < n; k += 8) {
        nfloat4 r = rec[k];                      // lanes 0-7 broadcast; wave = 128B line
        float dx = cx - r.x, dy = cy - r.y, dz = cz - r.z;
        int sp = __float_as_int(r.w);
        float d2 = dx * dx + dy * dy + dz * dz;
        float d  = sqrtf(d2);
        // fc = (0.5*cos(d*pi/5)+0.5)^2 via the native cos pipe:
        // cos(d*pi/5) = cos(2*pi * (d/10)) -> v_cos_f32 takes revolutions.
        float c  = 0.5f * __builtin_amdgcn_cosf(d * 0.1f) + 0.5f;
        float fc = c * c;
        int ti = sp * NWAVE + w;
        float t = d - s_rs[ti];
        float g = fc * s_pm[ti] * __expf(-s_ia[ti] * t * t);   // v_exp_f32 pipe
        a0 += g;
        a1 += g * dx; a2 += g * dy; a3 += g * dz;
        a4 += g * dx * dx; a5 += g * dx * dy; a6 += g * dx * dz;
        a7 += g * dy * dy; a8 += g * dy * dz; a9 += g * dz * dz;
    }

#define RED(v) { v += __shfl_xor(v, 8); v += __shfl_xor(v, 16); v += __shfl_xor(v, 32); }
    RED(a0) RED(a1) RED(a2) RED(a3) RED(a4)
    RED(a5) RED(a6) RED(a7) RED(a8) RED(a9)
#undef RED

    if (rsub == 0) {
        float* o = out + (size_t)atom * 24;
        o[w]      = a0 * a0;
        o[8 + w]  = a1 * a1 + a2 * a2 + a3 * a3;
        o[16 + w] = a4 * a4 + a7 * a7 + a9 * a9
                  + 2.0f * (a5 * a5 + a6 * a6 + a8 * a8);
    }
}

extern "C" void kernel_launch(void* const* d_in, const int* in_sizes, int n_in,
                              void* d_out, int out_size, void* d_ws, size_t ws_size,
                              hipStream_t stream)
{
    const float* cart      = (const float*)d_in[0];
    // d_in[1] = numatoms (unused by reference math)
    const int*   species   = (const int*)d_in[2];
    const int*   atom_index= (const int*)d_in[3];
    const float* shifts    = (const float*)d_in[4];
    const float* rs        = (const float*)d_in[5];
    const float* inta      = (const float*)d_in[6];
    const float* params    = (const float*)d_in[7];
    float* out = (float*)d_out;

    char* ws = (char*)d_ws;
    int*     cursors = (int*)ws;
    nfloat4* records = (nfloat4*)(ws + WS_OFF_RECORDS);

    zero_kernel<<<TOTATOM / 1024, 256, 0, stream>>>((int4*)cursors);
    scatter_kernel<<<NPAIR / 256, 256, 0, stream>>>(
        atom_index, shifts, cart, species, cursors, records);
    density_kernel<<<TOTATOM / 4, 256, 0, stream>>>(
        records, cursors, cart, rs, inta, params, out);
}